// Round 15
// baseline (119.123 us; speedup 1.0000x reference)
//
#include <hip/hip_runtime.h>
#include <hip/hip_bf16.h>
#include <math.h>

typedef unsigned short u16;
typedef __attribute__((ext_vector_type(8))) short bf16x8;  // 8 bf16 (4 VGPRs)
typedef __attribute__((ext_vector_type(4))) float f32x4;   // 4 f32 acc

#define DEVI __device__ __forceinline__

constexpr int NV = 4;
constexpr int NB = 4096;
constexpr int ND = 1024;
constexpr int NH = 512;
constexpr int NC = 50;
constexpr int NSAMP = 10000;
constexpr int NCP = 64;  // padded C for MFMA N-dim

DEVI u16 to_bf16(float f) {
  union { float f; unsigned u; } v; v.f = f;
  unsigned r = v.u + 0x7fffu + ((v.u >> 16) & 1u);  // RNE
  return (u16)(r >> 16);
}

// compiler-native cast: emits v_cvt (pairs to v_cvt_pk_bf16_f32), RNE
DEVI u16 cvt_bf16(float f) {
  __hip_bfloat16 h = __float2bfloat16(f);
  return *reinterpret_cast<u16*>(&h);
}

DEVI float wsum(float x) {
#pragma unroll
  for (int m = 32; m > 0; m >>= 1) x += __shfl_xor(x, m, 64);
  return x;
}

#define GLD_LDS16(gsrc, ldst)                                                  \
  __builtin_amdgcn_global_load_lds(                                            \
      (const __attribute__((address_space(1))) void*)(gsrc),                   \
      (__attribute__((address_space(3))) void*)(ldst), 16, 0, 0)

// ---------------- merged prep: W1 transpose (y<16) + W2 pad/cvt (y==16)
// grid (32, 17, 4), block (32, 8)
__global__ __launch_bounds__(256) void k_prep(const float* __restrict__ W1,
                                              const float* __restrict__ W2,
                                              u16* __restrict__ W1T,
                                              u16* __restrict__ W2T) {
  __shared__ float tile[32][33];
  const int v = blockIdx.z;
  const int tx = threadIdx.x, ty = threadIdx.y;  // (32, 8)
  if (blockIdx.y < NH / 32) {
    // ---- W1 (V,D,H) -> (V,H,D) bf16
    const int d0 = blockIdx.x * 32;
    const int h0 = blockIdx.y * 32;
    const float* src = W1 + (size_t)v * ND * NH;
    u16* dst = W1T + (size_t)v * NH * ND;
#pragma unroll
    for (int j = 0; j < 32; j += 8)
      tile[ty + j][tx] = src[(size_t)(d0 + ty + j) * NH + h0 + tx];
    __syncthreads();
#pragma unroll
    for (int j = 0; j < 32; j += 8)
      dst[(size_t)(h0 + ty + j) * ND + d0 + tx] = to_bf16(tile[tx][ty + j]);
  } else {
    // ---- W2 (V,H,C) -> (V,64,H) bf16 zero-pad; 32 blocks x 256 thr x 4 elems
    const int tid = ty * 32 + tx;
#pragma unroll
    for (int i = 0; i < 4; ++i) {
      int e = blockIdx.x * 1024 + i * 256 + tid;  // 0..32767 = c*NH + h
      int h = e % NH;
      int c = e / NH;  // 0..63
      float val = (c < NC) ? W2[((size_t)v * NH + h) * NC + c] : 0.f;
      W2T[(size_t)v * NCP * NH + e] = to_bf16(val);
    }
  }
}

// --------------------------------------------------- GEMM1: h=relu(x@W1+b1)
// r13 config (PROVEN 89.6): BM=128 x BN=256, 512 thr, 8 waves of 64x64,
// single-buffer 2-barrier K-loop, T14 A-reg prefetch, B via gld_lds.
__global__ __launch_bounds__(512) void k_gemm1(const float* __restrict__ Xf,
                                               const u16* __restrict__ W1T,
                                               const float* __restrict__ b1,
                                               u16* __restrict__ Hb) {
  constexpr int BM = 128, BN = 256, BK = 32;
  const int v = blockIdx.z;
  const int m0 = blockIdx.x * BM;
  const int n0 = blockIdx.y * BN;
  __shared__ u16 As[BM][BK];  // 8 KB
  __shared__ u16 Bs[BN][BK];  // 16 KB
  const float* Ag = Xf + (size_t)v * NB * ND + (size_t)m0 * ND;
  const u16* Bg = W1T + (size_t)v * NH * ND + (size_t)n0 * ND;
  const int tid = threadIdx.x;
  const int lane = tid & 63;
  const int wv = tid >> 6;             // 0..7
  const int wr = wv >> 2, wc = wv & 3; // wave sub-tile (2 x 4 of 64x64)
  const int rA = tid >> 2;             // 0..127 (1 row / thread)
  const int cA = (tid & 3) * 8;        // 8 f32 per thread

  f32x4 acc[4][4] = {};

  // prologue: prefetch A-tile k0=0 into registers (2 x float4 = 8 f32)
  float4 pa0 = *(const float4*)(Ag + (size_t)rA * ND + cA);
  float4 pa1 = *(const float4*)(Ag + (size_t)rA * ND + cA + 4);

  for (int k0 = 0; k0 < ND; k0 += BK) {
    __syncthreads();  // previous iter's LDS reads done before overwrite
    // A: registers (already arrived) -> cvt -> LDS
    {
      ushort4 u0, u1;
      u0.x = cvt_bf16(pa0.x); u0.y = cvt_bf16(pa0.y);
      u0.z = cvt_bf16(pa0.z); u0.w = cvt_bf16(pa0.w);
      u1.x = cvt_bf16(pa1.x); u1.y = cvt_bf16(pa1.y);
      u1.z = cvt_bf16(pa1.z); u1.w = cvt_bf16(pa1.w);
      *(ushort4*)&As[rA][cA]     = u0;
      *(ushort4*)&As[rA][cA + 4] = u1;
    }
    // B: async global->LDS, 2 x 16B per thread, slot pattern keeps the
    // per-wave LDS byte address linear in tid (gld_lds HW requirement).
#pragma unroll
    for (int i = 0; i < 2; ++i) {
      int s = tid + i * 512;  // 0..1023
      GLD_LDS16(Bg + (size_t)(s >> 2) * ND + k0 + (s & 3) * 8,
                &Bs[s >> 2][(s & 3) * 8]);
    }
    __syncthreads();  // drains lgkm (ds_write) + vmcnt (gld_lds)

    // T14: issue NEXT tile's A loads now; latency hides under MFMA phase.
    if (k0 + BK < ND) {
      pa0 = *(const float4*)(Ag + (size_t)rA * ND + k0 + BK + cA);
      pa1 = *(const float4*)(Ag + (size_t)rA * ND + k0 + BK + cA + 4);
    }

    const int fr = lane & 15;
    const int kb = (lane >> 4) * 8;
    bf16x8 af[4], bf[4];
#pragma unroll
    for (int mi = 0; mi < 4; ++mi)
      af[mi] = *(const bf16x8*)&As[wr * 64 + mi * 16 + fr][kb];
#pragma unroll
    for (int ni = 0; ni < 4; ++ni)
      bf[ni] = *(const bf16x8*)&Bs[wc * 64 + ni * 16 + fr][kb];
#pragma unroll
    for (int mi = 0; mi < 4; ++mi)
#pragma unroll
      for (int ni = 0; ni < 4; ++ni)
        acc[mi][ni] = __builtin_amdgcn_mfma_f32_16x16x32_bf16(
            af[mi], bf[ni], acc[mi][ni], 0, 0, 0);
  }

  // C/D layout (verified): col = lane&15, row = (lane>>4)*4 + reg
  const int frow = (lane >> 4) * 4;
  const int fcol = lane & 15;
#pragma unroll
  for (int mi = 0; mi < 4; ++mi) {
#pragma unroll
    for (int ni = 0; ni < 4; ++ni) {
      const int n = n0 + wc * 64 + ni * 16 + fcol;
      const float bias = b1[v * NH + n];
#pragma unroll
      for (int j = 0; j < 4; ++j) {
        const int m = m0 + wr * 64 + mi * 16 + frow + j;
        float val = fmaxf(acc[mi][ni][j] + bias, 0.f);
        Hb[(size_t)v * NB * NH + (size_t)m * NH + n] = to_bf16(val);
      }
    }
  }
}

// -------- GEMM2: evidence = softplus(h@W2+b2), N=64 (round-7 structure)
__global__ __launch_bounds__(256) void k_gemm2(const u16* __restrict__ Hb,
                                               const u16* __restrict__ W2T,
                                               const float* __restrict__ b2,
                                               float* __restrict__ out_ev) {
  constexpr int BM = 64, BK = 32;
  const int v = blockIdx.z;
  const int m0 = blockIdx.x * BM;
  __shared__ u16 As[BM][BK];    // 4 KB
  __shared__ u16 Bs[NCP][BK];   // 4 KB
  const u16* Ag = Hb + (size_t)v * NB * NH + (size_t)m0 * NH;
  const u16* Bg = W2T + (size_t)v * NCP * NH;
  const int tid = threadIdx.x;
  const int lane = tid & 63;
  const int wv = tid >> 6;
  const int r = tid >> 2;
  const int c8 = (tid & 3) * 8;

  f32x4 acc[4] = {};

  for (int k0 = 0; k0 < NH; k0 += BK) {
    __syncthreads();
    GLD_LDS16(Ag + (size_t)r * NH + k0 + c8, &As[r][c8]);
    GLD_LDS16(Bg + (size_t)r * NH + k0 + c8, &Bs[r][c8]);
    __syncthreads();

    const int fr = lane & 15;
    const int kb = (lane >> 4) * 8;
    bf16x8 af = *(const bf16x8*)&As[wv * 16 + fr][kb];
#pragma unroll
    for (int ni = 0; ni < 4; ++ni) {
      bf16x8 bf = *(const bf16x8*)&Bs[ni * 16 + fr][kb];
      acc[ni] = __builtin_amdgcn_mfma_f32_16x16x32_bf16(af, bf, acc[ni], 0, 0, 0);
    }
  }

  const int frow = (lane >> 4) * 4;
  const int fcol = lane & 15;
#pragma unroll
  for (int ni = 0; ni < 4; ++ni) {
    const int n = ni * 16 + fcol;
    if (n < NC) {
      const float bias = b2[v * NC + n];
#pragma unroll
      for (int j = 0; j < 4; ++j) {
        const int m = m0 + wv * 16 + frow + j;
        float x = acc[ni][j] + bias;
        // stable softplus, matches jax.nn.softplus
        float sp = fmaxf(x, 0.f) + log1pf(expf(-fabsf(x)));
        out_ev[(size_t)v * NB * NC + (size_t)m * NC + n] = sp;
      }
    }
  }
}

// ------------- fused transfer + DS-combine: wave = one batch row b
// (round-7 proven version: high TLP, no LDS, no staging)
__global__ __launch_bounds__(256) void k_tc(const float* __restrict__ evf,
                                            const float* __restrict__ mats,
                                            const int* __restrict__ idx,
                                            float* __restrict__ out_tr,
                                            float* __restrict__ out_ea) {
  const int b = blockIdx.x * 4 + (threadIdx.x >> 6);
  const int lane = threadIdx.x & 63;
  if (b >= NB) return;
  const bool act = lane < NC;
  const float Kf = (float)NC;
  const int ix = idx[b];

  float ta[NV];
#pragma unroll
  for (int v = 0; v < NV; ++v) {
    float acc = 0.f;
    if (act) {
      const float* e = evf + ((size_t)v * NB + b) * NC;
      const float* M = mats + ((size_t)v * NSAMP + ix) * NC * NC;
#pragma unroll
      for (int c = 0; c < NC; ++c)
        acc = fmaf(e[c], M[c * NC + lane], acc);
      out_tr[((size_t)v * NB + b) * NC + lane] = acc;
    }
    ta[v] = act ? acc + 1.0f : 0.0f;
  }

  float alpha = ta[0];
#pragma unroll
  for (int v = 1; v < NV; ++v) {
    float a2 = ta[v];
    float S1 = wsum(act ? alpha : 0.f);
    float S2 = wsum(act ? a2 : 0.f);
    float b1v = act ? (alpha - 1.f) / S1 : 0.f;
    float b2v = act ? (a2 - 1.f) / S2 : 0.f;
    float u1 = Kf / S1, u2 = Kf / S2;
    float sb1 = wsum(b1v);
    float sb2 = wsum(b2v);
    float sb12 = wsum(b1v * b2v);
    float Cconf = sb1 * sb2 - sb12;
    float denom = 1.f - Cconf;
    float b_a = (b1v * b2v + b1v * u2 + b2v * u1) / denom;
    float u_a = u1 * u2 / denom;
    float S_a = Kf / u_a;
    alpha = b_a * S_a + 1.f;  // e_a + 1
  }
  if (act) out_ea[(size_t)b * NC + lane] = alpha - 1.f;
}

// ---------------------------------------------------------------------------
extern "C" void kernel_launch(void* const* d_in, const int* in_sizes, int n_in,
                              void* d_out, int out_size, void* d_ws, size_t ws_size,
                              hipStream_t stream) {
  // Bind inputs BY ELEMENT COUNT (all distinct) — immune to order changes.
  const float *x = nullptr, *W1 = nullptr, *b1 = nullptr, *W2 = nullptr,
              *b2 = nullptr, *mats = nullptr;
  const int* idx = nullptr;
  for (int i = 0; i < n_in; ++i) {
    switch (in_sizes[i]) {
      case 16777216:  x    = (const float*)d_in[i]; break;  // V*B*D
      case 4096:      idx  = (const int*)d_in[i];   break;  // B
      case 2097152:   W1   = (const float*)d_in[i]; break;  // V*D*H
      case 2048:      b1   = (const float*)d_in[i]; break;  // V*H
      case 102400:    W2   = (const float*)d_in[i]; break;  // V*H*C
      case 200:       b2   = (const float*)d_in[i]; break;  // V*C
      case 100000000: mats = (const float*)d_in[i]; break;  // V*S*C*C
      default: break;
    }
  }
  if (!x || !idx || !W1 || !b1 || !W2 || !b2 || !mats) return;

  char* ws = (char*)d_ws;
  // ws layout (bytes): w1t bf16 4194304; w2t bf16 262144; hb bf16 16777216
  u16* w1t = (u16*)(ws + 0);
  u16* w2t = (u16*)(ws + 4194304);
  u16* hb  = (u16*)(ws + 4456448);

  // d_out is FLOAT32: [transferred (V,B,C) | evidence_a (B,C) | evidence (V,B,C)]
  float* out_tr = (float*)d_out;
  float* out_ea = out_tr + (size_t)NV * NB * NC;
  float* out_ev = out_ea + (size_t)NB * NC;

  k_prep<<<dim3(32, NH / 32 + 1, NV), dim3(32, 8), 0, stream>>>(W1, W2, w1t, w2t);
  // MEASUREMENT ROUND: gemm1 launched TWICE (idempotent — hb fully
  // overwritten with identical values). dur delta vs r13 = t_warm(gemm1),
  // isolating schedule/VALU cost from cold-HBM cost. Decision rule in notes.
  k_gemm1<<<dim3(NB / 128, NH / 256, NV), 512, 0, stream>>>(x, w1t, b1, hb);
  k_gemm1<<<dim3(NB / 128, NH / 256, NV), 512, 0, stream>>>(x, w1t, b1, hb);
  k_gemm2<<<dim3(NB / 64, 1, NV), 256, 0, stream>>>(hb, w2t, b2, out_ev);
  k_tc<<<NB / 4, 256, 0, stream>>>(out_ev, mats, idx, out_tr, out_ea);
}

// Round 16
// 92.700 us; speedup vs baseline: 1.2850x; 1.2850x over previous
//
#include <hip/hip_runtime.h>
#include <hip/hip_bf16.h>
#include <math.h>

typedef unsigned short u16;
typedef __attribute__((ext_vector_type(8))) short bf16x8;  // 8 bf16 (4 VGPRs)
typedef __attribute__((ext_vector_type(4))) float f32x4;   // 4 f32 acc

#define DEVI __device__ __forceinline__

constexpr int NV = 4;
constexpr int NB = 4096;
constexpr int ND = 1024;
constexpr int NH = 512;
constexpr int NC = 50;
constexpr int NSAMP = 10000;
constexpr int NCP = 64;  // padded C for MFMA N-dim

DEVI u16 to_bf16(float f) {
  union { float f; unsigned u; } v; v.f = f;
  unsigned r = v.u + 0x7fffu + ((v.u >> 16) & 1u);  // RNE
  return (u16)(r >> 16);
}

// compiler-native cast: emits v_cvt (pairs to v_cvt_pk_bf16_f32), RNE
DEVI u16 cvt_bf16(float f) {
  __hip_bfloat16 h = __float2bfloat16(f);
  return *reinterpret_cast<u16*>(&h);
}

DEVI float wsum(float x) {
#pragma unroll
  for (int m = 32; m > 0; m >>= 1) x += __shfl_xor(x, m, 64);
  return x;
}

#define GLD_LDS16(gsrc, ldst)                                                  \
  __builtin_amdgcn_global_load_lds(                                            \
      (const __attribute__((address_space(1))) void*)(gsrc),                   \
      (__attribute__((address_space(3))) void*)(ldst), 16, 0, 0)

// ---------------- merged prep: W1 transpose (y<16) + W2 pad/cvt (y==16)
// grid (32, 17, 4), block (32, 8)
__global__ __launch_bounds__(256) void k_prep(const float* __restrict__ W1,
                                              const float* __restrict__ W2,
                                              u16* __restrict__ W1T,
                                              u16* __restrict__ W2T) {
  __shared__ float tile[32][33];
  const int v = blockIdx.z;
  const int tx = threadIdx.x, ty = threadIdx.y;  // (32, 8)
  if (blockIdx.y < NH / 32) {
    // ---- W1 (V,D,H) -> (V,H,D) bf16
    const int d0 = blockIdx.x * 32;
    const int h0 = blockIdx.y * 32;
    const float* src = W1 + (size_t)v * ND * NH;
    u16* dst = W1T + (size_t)v * NH * ND;
#pragma unroll
    for (int j = 0; j < 32; j += 8)
      tile[ty + j][tx] = src[(size_t)(d0 + ty + j) * NH + h0 + tx];
    __syncthreads();
#pragma unroll
    for (int j = 0; j < 32; j += 8)
      dst[(size_t)(h0 + ty + j) * ND + d0 + tx] = to_bf16(tile[tx][ty + j]);
  } else {
    // ---- W2 (V,H,C) -> (V,64,H) bf16 zero-pad; 32 blocks x 256 thr x 4 elems
    const int tid = ty * 32 + tx;
#pragma unroll
    for (int i = 0; i < 4; ++i) {
      int e = blockIdx.x * 1024 + i * 256 + tid;  // 0..32767 = c*NH + h
      int h = e % NH;
      int c = e / NH;  // 0..63
      float val = (c < NC) ? W2[((size_t)v * NH + h) * NC + c] : 0.f;
      W2T[(size_t)v * NCP * NH + e] = to_bf16(val);
    }
  }
}

// --------------------------------------------------- GEMM1: h=relu(x@W1+b1)
// T4 counted-vmcnt pipeline: double-buffered LDS, raw s_barriers, NO
// vmcnt(0)/lgkmcnt(0) drain in the main loop. B loads issued one full MFMA
// phase before their wait (vmcnt(4)). m201 wait-then-barrier pattern.
__global__ __launch_bounds__(512) void k_gemm1(const float* __restrict__ Xf,
                                               const u16* __restrict__ W1T,
                                               const float* __restrict__ b1,
                                               u16* __restrict__ Hb) {
  constexpr int BM = 128, BN = 256, BK = 32;
  constexpr int NT = ND / BK;  // 32 K-steps
  const int v = blockIdx.z;
  const int m0 = blockIdx.x * BM;
  const int n0 = blockIdx.y * BN;
  __shared__ u16 As[2][BM][BK];  // 2 x 8 KB
  __shared__ u16 Bs[2][BN][BK];  // 2 x 16 KB
  const float* Ag = Xf + (size_t)v * NB * ND + (size_t)m0 * ND;
  const u16* Bg = W1T + (size_t)v * NH * ND + (size_t)n0 * ND;
  const int tid = threadIdx.x;
  const int lane = tid & 63;
  const int wv = tid >> 6;             // 0..7
  const int wr = wv >> 2, wc = wv & 3; // wave sub-tile (2 x 4 of 64x64)
  const int rA = tid >> 2;             // 0..127 (1 row / thread)
  const int cA = (tid & 3) * 8;        // 8 f32 per thread

  f32x4 acc[4][4] = {};
  float4 pa0, pa1;

  auto LOAD_PA = [&](int k) {
    pa0 = *(const float4*)(Ag + (size_t)rA * ND + k + cA);
    pa1 = *(const float4*)(Ag + (size_t)rA * ND + k + cA + 4);
  };
  auto STAGE_A = [&](int buf) {  // cvt pa -> As[buf] (2 x ds_write_b64)
    ushort4 u0, u1;
    u0.x = cvt_bf16(pa0.x); u0.y = cvt_bf16(pa0.y);
    u0.z = cvt_bf16(pa0.z); u0.w = cvt_bf16(pa0.w);
    u1.x = cvt_bf16(pa1.x); u1.y = cvt_bf16(pa1.y);
    u1.z = cvt_bf16(pa1.z); u1.w = cvt_bf16(pa1.w);
    *(ushort4*)&As[buf][rA][cA]     = u0;
    *(ushort4*)&As[buf][rA][cA + 4] = u1;
  };
  auto STAGE_B = [&](int buf, int k0) {  // 2 x gld_lds, wave-linear dest
#pragma unroll
    for (int i = 0; i < 2; ++i) {
      int s = tid + i * 512;  // 0..1023; LDS byte = s*16 (lane-stride 16 ok)
      GLD_LDS16(Bg + (size_t)(s >> 2) * ND + k0 + (s & 3) * 8,
                &Bs[buf][s >> 2][(s & 3) * 8]);
    }
  };
  auto COMPUTE = [&](int buf) {
    const int fr = lane & 15;
    const int kb = (lane >> 4) * 8;
    bf16x8 af[4], bf[4];
#pragma unroll
    for (int mi = 0; mi < 4; ++mi)
      af[mi] = *(const bf16x8*)&As[buf][wr * 64 + mi * 16 + fr][kb];
#pragma unroll
    for (int ni = 0; ni < 4; ++ni)
      bf[ni] = *(const bf16x8*)&Bs[buf][wc * 64 + ni * 16 + fr][kb];
#pragma unroll
    for (int mi = 0; mi < 4; ++mi)
#pragma unroll
      for (int ni = 0; ni < 4; ++ni)
        acc[mi][ni] = __builtin_amdgcn_mfma_f32_16x16x32_bf16(
            af[mi], bf[ni], acc[mi][ni], 0, 0, 0);
  };

  // ---- prologue: stage buf0 (k=0); prefetch pa(k=32). pa(k0) issued first,
  // B glds after, so compiler's pa-wait at STAGE_A leaves B glds in flight.
  LOAD_PA(0);
  STAGE_B(0, 0);
  STAGE_A(0);          // compiler inserts vmcnt wait for pa(k0) here
  LOAD_PA(BK);
  // No drain here: t=0's vmcnt(4) covers Bs[0]; lgkmcnt(2) covers As[0].

  // ---- main loop t = 0..29 (uniform literal counts)
  for (int t = 0; t < NT - 2; ++t) {
    const int cur = t & 1, nxt = cur ^ 1;
    __builtin_amdgcn_s_barrier();  // prev iter's frag reads done before write
    STAGE_A(nxt);                  // cvt pa(k_{t+1}); compiler waits pa only
    LOAD_PA((t + 2) * BK);         // 2 vm (older than B glds below)
    STAGE_B(nxt, (t + 1) * BK);    // 2 vm
    // my Bs[cur] (issued last iter) done; 4 newer (pa + Bs[nxt]) in flight;
    // my As[cur] writes done; 2 newer (As[nxt]) may be outstanding.
    asm volatile("s_waitcnt vmcnt(4) lgkmcnt(2)" ::: "memory");
    __builtin_amdgcn_sched_barrier(0);
    __builtin_amdgcn_s_barrier();  // => ALL waves' cur staging visible
    __builtin_amdgcn_sched_barrier(0);
    COMPUTE(cur);
  }
  // ---- t = 30: stage last tile (no pa prefetch)
  __builtin_amdgcn_s_barrier();
  STAGE_A(1);                      // pa holds k=992 (loaded at t=29)
  STAGE_B(1, (NT - 1) * BK);
  asm volatile("s_waitcnt vmcnt(2) lgkmcnt(2)" ::: "memory");
  __builtin_amdgcn_sched_barrier(0);
  __builtin_amdgcn_s_barrier();
  __builtin_amdgcn_sched_barrier(0);
  COMPUTE(0);
  // ---- t = 31: no staging; drain remaining
  __builtin_amdgcn_s_barrier();
  asm volatile("s_waitcnt vmcnt(0) lgkmcnt(0)" ::: "memory");
  __builtin_amdgcn_sched_barrier(0);
  __builtin_amdgcn_s_barrier();
  __builtin_amdgcn_sched_barrier(0);
  COMPUTE(1);

  // C/D layout (verified): col = lane&15, row = (lane>>4)*4 + reg
  const int frow = (lane >> 4) * 4;
  const int fcol = lane & 15;
#pragma unroll
  for (int mi = 0; mi < 4; ++mi) {
#pragma unroll
    for (int ni = 0; ni < 4; ++ni) {
      const int n = n0 + wc * 64 + ni * 16 + fcol;
      const float bias = b1[v * NH + n];
#pragma unroll
      for (int j = 0; j < 4; ++j) {
        const int m = m0 + wr * 64 + mi * 16 + frow + j;
        float val = fmaxf(acc[mi][ni][j] + bias, 0.f);
        Hb[(size_t)v * NB * NH + (size_t)m * NH + n] = to_bf16(val);
      }
    }
  }
}

// -------- GEMM2: evidence = softplus(h@W2+b2), N=64 (round-7 structure)
__global__ __launch_bounds__(256) void k_gemm2(const u16* __restrict__ Hb,
                                               const u16* __restrict__ W2T,
                                               const float* __restrict__ b2,
                                               float* __restrict__ out_ev) {
  constexpr int BM = 64, BK = 32;
  const int v = blockIdx.z;
  const int m0 = blockIdx.x * BM;
  __shared__ u16 As[BM][BK];    // 4 KB
  __shared__ u16 Bs[NCP][BK];   // 4 KB
  const u16* Ag = Hb + (size_t)v * NB * NH + (size_t)m0 * NH;
  const u16* Bg = W2T + (size_t)v * NCP * NH;
  const int tid = threadIdx.x;
  const int lane = tid & 63;
  const int wv = tid >> 6;
  const int r = tid >> 2;
  const int c8 = (tid & 3) * 8;

  f32x4 acc[4] = {};

  for (int k0 = 0; k0 < NH; k0 += BK) {
    __syncthreads();
    GLD_LDS16(Ag + (size_t)r * NH + k0 + c8, &As[r][c8]);
    GLD_LDS16(Bg + (size_t)r * NH + k0 + c8, &Bs[r][c8]);
    __syncthreads();

    const int fr = lane & 15;
    const int kb = (lane >> 4) * 8;
    bf16x8 af = *(const bf16x8*)&As[wv * 16 + fr][kb];
#pragma unroll
    for (int ni = 0; ni < 4; ++ni) {
      bf16x8 bf = *(const bf16x8*)&Bs[ni * 16 + fr][kb];
      acc[ni] = __builtin_amdgcn_mfma_f32_16x16x32_bf16(af, bf, acc[ni], 0, 0, 0);
    }
  }

  const int frow = (lane >> 4) * 4;
  const int fcol = lane & 15;
#pragma unroll
  for (int ni = 0; ni < 4; ++ni) {
    const int n = ni * 16 + fcol;
    if (n < NC) {
      const float bias = b2[v * NC + n];
#pragma unroll
      for (int j = 0; j < 4; ++j) {
        const int m = m0 + wv * 16 + frow + j;
        float x = acc[ni][j] + bias;
        // stable softplus, matches jax.nn.softplus
        float sp = fmaxf(x, 0.f) + log1pf(expf(-fabsf(x)));
        out_ev[(size_t)v * NB * NC + (size_t)m * NC + n] = sp;
      }
    }
  }
}

// ------------- fused transfer + DS-combine: wave = one batch row b
// (round-7 proven version: high TLP, no LDS, no staging)
__global__ __launch_bounds__(256) void k_tc(const float* __restrict__ evf,
                                            const float* __restrict__ mats,
                                            const int* __restrict__ idx,
                                            float* __restrict__ out_tr,
                                            float* __restrict__ out_ea) {
  const int b = blockIdx.x * 4 + (threadIdx.x >> 6);
  const int lane = threadIdx.x & 63;
  if (b >= NB) return;
  const bool act = lane < NC;
  const float Kf = (float)NC;
  const int ix = idx[b];

  float ta[NV];
#pragma unroll
  for (int v = 0; v < NV; ++v) {
    float acc = 0.f;
    if (act) {
      const float* e = evf + ((size_t)v * NB + b) * NC;
      const float* M = mats + ((size_t)v * NSAMP + ix) * NC * NC;
#pragma unroll
      for (int c = 0; c < NC; ++c)
        acc = fmaf(e[c], M[c * NC + lane], acc);
      out_tr[((size_t)v * NB + b) * NC + lane] = acc;
    }
    ta[v] = act ? acc + 1.0f : 0.0f;
  }

  float alpha = ta[0];
#pragma unroll
  for (int v = 1; v < NV; ++v) {
    float a2 = ta[v];
    float S1 = wsum(act ? alpha : 0.f);
    float S2 = wsum(act ? a2 : 0.f);
    float b1v = act ? (alpha - 1.f) / S1 : 0.f;
    float b2v = act ? (a2 - 1.f) / S2 : 0.f;
    float u1 = Kf / S1, u2 = Kf / S2;
    float sb1 = wsum(b1v);
    float sb2 = wsum(b2v);
    float sb12 = wsum(b1v * b2v);
    float Cconf = sb1 * sb2 - sb12;
    float denom = 1.f - Cconf;
    float b_a = (b1v * b2v + b1v * u2 + b2v * u1) / denom;
    float u_a = u1 * u2 / denom;
    float S_a = Kf / u_a;
    alpha = b_a * S_a + 1.f;  // e_a + 1
  }
  if (act) out_ea[(size_t)b * NC + lane] = alpha - 1.f;
}

// ---------------------------------------------------------------------------
extern "C" void kernel_launch(void* const* d_in, const int* in_sizes, int n_in,
                              void* d_out, int out_size, void* d_ws, size_t ws_size,
                              hipStream_t stream) {
  // Bind inputs BY ELEMENT COUNT (all distinct) — immune to order changes.
  const float *x = nullptr, *W1 = nullptr, *b1 = nullptr, *W2 = nullptr,
              *b2 = nullptr, *mats = nullptr;
  const int* idx = nullptr;
  for (int i = 0; i < n_in; ++i) {
    switch (in_sizes[i]) {
      case 16777216:  x    = (const float*)d_in[i]; break;  // V*B*D
      case 4096:      idx  = (const int*)d_in[i];   break;  // B
      case 2097152:   W1   = (const float*)d_in[i]; break;  // V*D*H
      case 2048:      b1   = (const float*)d_in[i]; break;  // V*H
      case 102400:    W2   = (const float*)d_in[i]; break;  // V*H*C
      case 200:       b2   = (const float*)d_in[i]; break;  // V*C
      case 100000000: mats = (const float*)d_in[i]; break;  // V*S*C*C
      default: break;
    }
  }
  if (!x || !idx || !W1 || !b1 || !W2 || !b2 || !mats) return;

  char* ws = (char*)d_ws;
  // ws layout (bytes): w1t bf16 4194304; w2t bf16 262144; hb bf16 16777216
  u16* w1t = (u16*)(ws + 0);
  u16* w2t = (u16*)(ws + 4194304);
  u16* hb  = (u16*)(ws + 4456448);

  // d_out is FLOAT32: [transferred (V,B,C) | evidence_a (B,C) | evidence (V,B,C)]
  float* out_tr = (float*)d_out;
  float* out_ea = out_tr + (size_t)NV * NB * NC;
  float* out_ev = out_ea + (size_t)NB * NC;

  k_prep<<<dim3(32, NH / 32 + 1, NV), dim3(32, 8), 0, stream>>>(W1, W2, w1t, w2t);
  k_gemm1<<<dim3(NB / 128, NH / 256, NV), 512, 0, stream>>>(x, w1t, b1, hb);
  k_gemm2<<<dim3(NB / 64, 1, NV), 256, 0, stream>>>(hb, w2t, b2, out_ev);
  k_tc<<<NB / 4, 256, 0, stream>>>(out_ev, mats, idx, out_tr, out_ea);
}

// Round 17
// 89.263 us; speedup vs baseline: 1.3345x; 1.0385x over previous
//
#include <hip/hip_runtime.h>
#include <hip/hip_bf16.h>
#include <math.h>

typedef unsigned short u16;
typedef __attribute__((ext_vector_type(8))) short bf16x8;  // 8 bf16 (4 VGPRs)
typedef __attribute__((ext_vector_type(4))) float f32x4;   // 4 f32 acc

#define DEVI __device__ __forceinline__

constexpr int NV = 4;
constexpr int NB = 4096;
constexpr int ND = 1024;
constexpr int NH = 512;
constexpr int NC = 50;
constexpr int NSAMP = 10000;
constexpr int NCP = 64;  // padded C for MFMA N-dim

DEVI u16 to_bf16(float f) {
  union { float f; unsigned u; } v; v.f = f;
  unsigned r = v.u + 0x7fffu + ((v.u >> 16) & 1u);  // RNE
  return (u16)(r >> 16);
}

// compiler-native cast: emits v_cvt (pairs to v_cvt_pk_bf16_f32), RNE
DEVI u16 cvt_bf16(float f) {
  __hip_bfloat16 h = __float2bfloat16(f);
  return *reinterpret_cast<u16*>(&h);
}

DEVI float wsum(float x) {
#pragma unroll
  for (int m = 32; m > 0; m >>= 1) x += __shfl_xor(x, m, 64);
  return x;
}

#define GLD_LDS16(gsrc, ldst)                                                  \
  __builtin_amdgcn_global_load_lds(                                            \
      (const __attribute__((address_space(1))) void*)(gsrc),                   \
      (__attribute__((address_space(3))) void*)(ldst), 16, 0, 0)

// ---------------- merged prep: W1 transpose (y<16) + W2 pad/cvt (y==16)
// grid (32, 17, 4), block (32, 8)
__global__ __launch_bounds__(256) void k_prep(const float* __restrict__ W1,
                                              const float* __restrict__ W2,
                                              u16* __restrict__ W1T,
                                              u16* __restrict__ W2T) {
  __shared__ float tile[32][33];
  const int v = blockIdx.z;
  const int tx = threadIdx.x, ty = threadIdx.y;  // (32, 8)
  if (blockIdx.y < NH / 32) {
    // ---- W1 (V,D,H) -> (V,H,D) bf16
    const int d0 = blockIdx.x * 32;
    const int h0 = blockIdx.y * 32;
    const float* src = W1 + (size_t)v * ND * NH;
    u16* dst = W1T + (size_t)v * NH * ND;
#pragma unroll
    for (int j = 0; j < 32; j += 8)
      tile[ty + j][tx] = src[(size_t)(d0 + ty + j) * NH + h0 + tx];
    __syncthreads();
#pragma unroll
    for (int j = 0; j < 32; j += 8)
      dst[(size_t)(h0 + ty + j) * ND + d0 + tx] = to_bf16(tile[tx][ty + j]);
  } else {
    // ---- W2 (V,H,C) -> (V,64,H) bf16 zero-pad; 32 blocks x 256 thr x 4 elems
    const int tid = ty * 32 + tx;
#pragma unroll
    for (int i = 0; i < 4; ++i) {
      int e = blockIdx.x * 1024 + i * 256 + tid;  // 0..32767 = c*NH + h
      int h = e % NH;
      int c = e / NH;  // 0..63
      float val = (c < NC) ? W2[((size_t)v * NH + h) * NC + c] : 0.f;
      W2T[(size_t)v * NCP * NH + e] = to_bf16(val);
    }
  }
}

// --------------------------------------------------- GEMM1: h=relu(x@W1+b1)
// r13 config (PROVEN BEST, 89.6 us): BM=128 x BN=256, 512 thr, 8 waves of
// 64x64, single-buffer 2-barrier K-loop, T14 A-reg prefetch, B via gld_lds.
// Structural ledger: dbuf null (r8), BK=64 -8 (r11), 64x256 retile -3 (r14),
// no-LDS -55 (r10), counted-vmcnt -3 (r16). Warm cost 29.5us = 582 TF = the
// measured 2-phase structure ceiling (m233); next lever would be the full
// 8-phase+swizzle+setprio combo.
__global__ __launch_bounds__(512) void k_gemm1(const float* __restrict__ Xf,
                                               const u16* __restrict__ W1T,
                                               const float* __restrict__ b1,
                                               u16* __restrict__ Hb) {
  constexpr int BM = 128, BN = 256, BK = 32;
  const int v = blockIdx.z;
  const int m0 = blockIdx.x * BM;
  const int n0 = blockIdx.y * BN;
  __shared__ u16 As[BM][BK];  // 8 KB
  __shared__ u16 Bs[BN][BK];  // 16 KB
  const float* Ag = Xf + (size_t)v * NB * ND + (size_t)m0 * ND;
  const u16* Bg = W1T + (size_t)v * NH * ND + (size_t)n0 * ND;
  const int tid = threadIdx.x;
  const int lane = tid & 63;
  const int wv = tid >> 6;             // 0..7
  const int wr = wv >> 2, wc = wv & 3; // wave sub-tile (2 x 4 of 64x64)
  const int rA = tid >> 2;             // 0..127 (1 row / thread)
  const int cA = (tid & 3) * 8;        // 8 f32 per thread

  f32x4 acc[4][4] = {};

  // prologue: prefetch A-tile k0=0 into registers (2 x float4 = 8 f32)
  float4 pa0 = *(const float4*)(Ag + (size_t)rA * ND + cA);
  float4 pa1 = *(const float4*)(Ag + (size_t)rA * ND + cA + 4);

  for (int k0 = 0; k0 < ND; k0 += BK) {
    __syncthreads();  // previous iter's LDS reads done before overwrite
    // A: registers (already arrived) -> cvt -> LDS
    {
      ushort4 u0, u1;
      u0.x = cvt_bf16(pa0.x); u0.y = cvt_bf16(pa0.y);
      u0.z = cvt_bf16(pa0.z); u0.w = cvt_bf16(pa0.w);
      u1.x = cvt_bf16(pa1.x); u1.y = cvt_bf16(pa1.y);
      u1.z = cvt_bf16(pa1.z); u1.w = cvt_bf16(pa1.w);
      *(ushort4*)&As[rA][cA]     = u0;
      *(ushort4*)&As[rA][cA + 4] = u1;
    }
    // B: async global->LDS, 2 x 16B per thread, slot pattern keeps the
    // per-wave LDS byte address linear in tid (gld_lds HW requirement).
#pragma unroll
    for (int i = 0; i < 2; ++i) {
      int s = tid + i * 512;  // 0..1023
      GLD_LDS16(Bg + (size_t)(s >> 2) * ND + k0 + (s & 3) * 8,
                &Bs[s >> 2][(s & 3) * 8]);
    }
    __syncthreads();  // drains lgkm (ds_write) + vmcnt (gld_lds)

    // T14: issue NEXT tile's A loads now; latency hides under MFMA phase.
    if (k0 + BK < ND) {
      pa0 = *(const float4*)(Ag + (size_t)rA * ND + k0 + BK + cA);
      pa1 = *(const float4*)(Ag + (size_t)rA * ND + k0 + BK + cA + 4);
    }

    const int fr = lane & 15;
    const int kb = (lane >> 4) * 8;
    bf16x8 af[4], bf[4];
#pragma unroll
    for (int mi = 0; mi < 4; ++mi)
      af[mi] = *(const bf16x8*)&As[wr * 64 + mi * 16 + fr][kb];
#pragma unroll
    for (int ni = 0; ni < 4; ++ni)
      bf[ni] = *(const bf16x8*)&Bs[wc * 64 + ni * 16 + fr][kb];
#pragma unroll
    for (int mi = 0; mi < 4; ++mi)
#pragma unroll
      for (int ni = 0; ni < 4; ++ni)
        acc[mi][ni] = __builtin_amdgcn_mfma_f32_16x16x32_bf16(
            af[mi], bf[ni], acc[mi][ni], 0, 0, 0);
  }

  // C/D layout (verified): col = lane&15, row = (lane>>4)*4 + reg
  const int frow = (lane >> 4) * 4;
  const int fcol = lane & 15;
#pragma unroll
  for (int mi = 0; mi < 4; ++mi) {
#pragma unroll
    for (int ni = 0; ni < 4; ++ni) {
      const int n = n0 + wc * 64 + ni * 16 + fcol;
      const float bias = b1[v * NH + n];
#pragma unroll
      for (int j = 0; j < 4; ++j) {
        const int m = m0 + wr * 64 + mi * 16 + frow + j;
        float val = fmaxf(acc[mi][ni][j] + bias, 0.f);
        Hb[(size_t)v * NB * NH + (size_t)m * NH + n] = to_bf16(val);
      }
    }
  }
}

// -------- GEMM2: evidence = softplus(h@W2+b2), N=64 (round-7 structure)
__global__ __launch_bounds__(256) void k_gemm2(const u16* __restrict__ Hb,
                                               const u16* __restrict__ W2T,
                                               const float* __restrict__ b2,
                                               float* __restrict__ out_ev) {
  constexpr int BM = 64, BK = 32;
  const int v = blockIdx.z;
  const int m0 = blockIdx.x * BM;
  __shared__ u16 As[BM][BK];    // 4 KB
  __shared__ u16 Bs[NCP][BK];   // 4 KB
  const u16* Ag = Hb + (size_t)v * NB * NH + (size_t)m0 * NH;
  const u16* Bg = W2T + (size_t)v * NCP * NH;
  const int tid = threadIdx.x;
  const int lane = tid & 63;
  const int wv = tid >> 6;
  const int r = tid >> 2;
  const int c8 = (tid & 3) * 8;

  f32x4 acc[4] = {};

  for (int k0 = 0; k0 < NH; k0 += BK) {
    __syncthreads();
    GLD_LDS16(Ag + (size_t)r * NH + k0 + c8, &As[r][c8]);
    GLD_LDS16(Bg + (size_t)r * NH + k0 + c8, &Bs[r][c8]);
    __syncthreads();

    const int fr = lane & 15;
    const int kb = (lane >> 4) * 8;
    bf16x8 af = *(const bf16x8*)&As[wv * 16 + fr][kb];
#pragma unroll
    for (int ni = 0; ni < 4; ++ni) {
      bf16x8 bf = *(const bf16x8*)&Bs[ni * 16 + fr][kb];
      acc[ni] = __builtin_amdgcn_mfma_f32_16x16x32_bf16(af, bf, acc[ni], 0, 0, 0);
    }
  }

  const int frow = (lane >> 4) * 4;
  const int fcol = lane & 15;
#pragma unroll
  for (int ni = 0; ni < 4; ++ni) {
    const int n = ni * 16 + fcol;
    if (n < NC) {
      const float bias = b2[v * NC + n];
#pragma unroll
      for (int j = 0; j < 4; ++j) {
        const int m = m0 + wv * 16 + frow + j;
        float x = acc[ni][j] + bias;
        // stable softplus, matches jax.nn.softplus
        float sp = fmaxf(x, 0.f) + log1pf(expf(-fabsf(x)));
        out_ev[(size_t)v * NB * NC + (size_t)m * NC + n] = sp;
      }
    }
  }
}

// ------------- fused transfer + DS-combine: wave = one batch row b
// (round-7 proven version: high TLP, no LDS, no staging)
__global__ __launch_bounds__(256) void k_tc(const float* __restrict__ evf,
                                            const float* __restrict__ mats,
                                            const int* __restrict__ idx,
                                            float* __restrict__ out_tr,
                                            float* __restrict__ out_ea) {
  const int b = blockIdx.x * 4 + (threadIdx.x >> 6);
  const int lane = threadIdx.x & 63;
  if (b >= NB) return;
  const bool act = lane < NC;
  const float Kf = (float)NC;
  const int ix = idx[b];

  float ta[NV];
#pragma unroll
  for (int v = 0; v < NV; ++v) {
    float acc = 0.f;
    if (act) {
      const float* e = evf + ((size_t)v * NB + b) * NC;
      const float* M = mats + ((size_t)v * NSAMP + ix) * NC * NC;
#pragma unroll
      for (int c = 0; c < NC; ++c)
        acc = fmaf(e[c], M[c * NC + lane], acc);
      out_tr[((size_t)v * NB + b) * NC + lane] = acc;
    }
    ta[v] = act ? acc + 1.0f : 0.0f;
  }

  float alpha = ta[0];
#pragma unroll
  for (int v = 1; v < NV; ++v) {
    float a2 = ta[v];
    float S1 = wsum(act ? alpha : 0.f);
    float S2 = wsum(act ? a2 : 0.f);
    float b1v = act ? (alpha - 1.f) / S1 : 0.f;
    float b2v = act ? (a2 - 1.f) / S2 : 0.f;
    float u1 = Kf / S1, u2 = Kf / S2;
    float sb1 = wsum(b1v);
    float sb2 = wsum(b2v);
    float sb12 = wsum(b1v * b2v);
    float Cconf = sb1 * sb2 - sb12;
    float denom = 1.f - Cconf;
    float b_a = (b1v * b2v + b1v * u2 + b2v * u1) / denom;
    float u_a = u1 * u2 / denom;
    float S_a = Kf / u_a;
    alpha = b_a * S_a + 1.f;  // e_a + 1
  }
  if (act) out_ea[(size_t)b * NC + lane] = alpha - 1.f;
}

// ---------------------------------------------------------------------------
extern "C" void kernel_launch(void* const* d_in, const int* in_sizes, int n_in,
                              void* d_out, int out_size, void* d_ws, size_t ws_size,
                              hipStream_t stream) {
  // Bind inputs BY ELEMENT COUNT (all distinct) — immune to order changes.
  const float *x = nullptr, *W1 = nullptr, *b1 = nullptr, *W2 = nullptr,
              *b2 = nullptr, *mats = nullptr;
  const int* idx = nullptr;
  for (int i = 0; i < n_in; ++i) {
    switch (in_sizes[i]) {
      case 16777216:  x    = (const float*)d_in[i]; break;  // V*B*D
      case 4096:      idx  = (const int*)d_in[i];   break;  // B
      case 2097152:   W1   = (const float*)d_in[i]; break;  // V*D*H
      case 2048:      b1   = (const float*)d_in[i]; break;  // V*H
      case 102400:    W2   = (const float*)d_in[i]; break;  // V*H*C
      case 200:       b2   = (const float*)d_in[i]; break;  // V*C
      case 100000000: mats = (const float*)d_in[i]; break;  // V*S*C*C
      default: break;
    }
  }
  if (!x || !idx || !W1 || !b1 || !W2 || !b2 || !mats) return;

  char* ws = (char*)d_ws;
  // ws layout (bytes): w1t bf16 4194304; w2t bf16 262144; hb bf16 16777216
  u16* w1t = (u16*)(ws + 0);
  u16* w2t = (u16*)(ws + 4194304);
  u16* hb  = (u16*)(ws + 4456448);

  // d_out is FLOAT32: [transferred (V,B,C) | evidence_a (B,C) | evidence (V,B,C)]
  float* out_tr = (float*)d_out;
  float* out_ea = out_tr + (size_t)NV * NB * NC;
  float* out_ev = out_ea + (size_t)NB * NC;

  k_prep<<<dim3(32, NH / 32 + 1, NV), dim3(32, 8), 0, stream>>>(W1, W2, w1t, w2t);
  k_gemm1<<<dim3(NB / 128, NH / 256, NV), 512, 0, stream>>>(x, w1t, b1, hb);
  k_gemm2<<<dim3(NB / 64, 1, NV), 256, 0, stream>>>(hb, w2t, b2, out_ev);
  k_tc<<<NB / 4, 256, 0, stream>>>(out_ev, mats, idx, out_tr, out_ea);
}